// Round 15
// baseline (915.075 us; speedup 1.0000x reference)
//
#include <hip/hip_runtime.h>
#include <hip/hip_bf16.h>
#include <math.h>

#define B_ 128
#define T_ 128
#define D_ 512
#define STEPS_ 255

#define REF_COMP 4096
#define REF_ZERO 8192

// LDS partition (bytes): W-ktiles 12..15 | c-buffer | zero pad
#define WOFF 0
#define COFF 131072
#define ZOFF 147456
#define LDS_USHORTS ((131072 + 16384 + 1024) / 2)

using short8   = __attribute__((ext_vector_type(8))) short;
using ushort8  = __attribute__((ext_vector_type(8))) unsigned short;
using ushort4v = __attribute__((ext_vector_type(4))) unsigned short;
using float4v  = __attribute__((ext_vector_type(4))) float;

__device__ __forceinline__ unsigned short rne_bf16(float f){
  union { float f; unsigned u; } v; v.f = f;
  unsigned u = v.u;
  u += 0x7FFFu + ((u >> 16) & 1u);
  return (unsigned short)(u >> 16);
}
__device__ __forceinline__ float bf2f(unsigned short u){
  union { unsigned u; float f; } x; x.u = ((unsigned)u) << 16; return x.f;
}
__device__ __forceinline__ float fast_tanh(float x){
  float xc = fminf(9.0f, fmaxf(-9.0f, x));
  float e  = __expf(2.0f * xc);
  return (e - 1.0f) * __builtin_amdgcn_rcpf(e + 1.0f);
}
// parity grouping: group-slot j -> batch row (evens first, then odds)
__device__ __forceinline__ int rowB(int j){ return (j < 64) ? (2*j) : (2*(j-64)+1); }

// ---------------- zero init: bitmaps / zero page -----------------------------
__global__ void k_zero(int* __restrict__ anyLR, int* __restrict__ gIter,
                       unsigned short* __restrict__ zeroPg){
  int t = threadIdx.x;
  for (int i = t; i < 1024; i += 256) anyLR[i] = 0;
  if (t < 16) gIter[t] = 0;
  for (int i = t; i < 1024; i += 256) zeroPg[i] = 0;
}

// ---------------- pre-pass: symbolic stack simulation (1 block / row) --------
// ref encoding: 0..127 = BUF idx; 4096+k = COMP k; 8192 = initial zero; -1 = none
__global__ __launch_bounds__(64) void k_prepass2(
    const int* __restrict__ tr,
    short* __restrict__ redL, short* __restrict__ redR,
    short* __restrict__ uL, short* __restrict__ uR,
    short* __restrict__ cL, short* __restrict__ cR,
    int* __restrict__ nred, int* __restrict__ encRef,
    int* __restrict__ gIter, int* __restrict__ anyLR){
  __shared__ int trs[STEPS_];
  int b = blockIdx.x, lane = threadIdx.x;
  for (int i = lane; i < STEPS_; i += 64) trs[i] = tr[b*STEPS_ + i];
  __syncthreads();
  if (lane != 0) return;
  short stk[T_ + 2];
  stk[0] = (short)REF_ZERO; stk[1] = (short)REF_ZERO;
  int ptr = 2, bptr = 0, k = 0;
  int g = (b & 1) ? 4 + ((b >> 1) >> 4) : ((b >> 1) >> 4);
  for (int t = 0; t < STEPS_; t++){
    int tt = trs[t];
    int rl = -1, rr = -1;
    if (tt == 0){                      // SHIFT
      int j = bptr; if (j > T_-1) j = T_-1;
      int wi = ptr; if (wi < 0) wi = 0; if (wi > T_+1) wi = T_+1;
      stk[wi] = (short)j;
      ptr++; bptr++;
    } else if (tt == 1){               // REDUCE
      int i1 = ptr-1; if (i1 < 0) i1 = 0; if (i1 > T_+1) i1 = T_+1;
      int i2 = ptr-2; if (i2 < 0) i2 = 0; if (i2 > T_+1) i2 = T_+1;
      rr = stk[i1]; rl = stk[i2];
      short sL = (rl >= 0 && rl < REF_COMP) ? (short)rl : (short)-1;   // static buf
      short sR = (rr >= 0 && rr < REF_COMP) ? (short)rr : (short)-1;
      short dL = (rl >= REF_COMP && rl < REF_ZERO) ? (short)(rl - REF_COMP) : (short)-1; // dyn comp
      short dR = (rr >= REF_COMP && rr < REF_ZERO) ? (short)(rr - REF_COMP) : (short)-1;
      uL[b*128 + k] = sL; uR[b*128 + k] = sR;
      cL[b*128 + k] = dL; cR[b*128 + k] = dR;
      int bits = (dL >= 0 ? 1 : 0) | (dR >= 0 ? 2 : 0);
      if (bits) atomicOr(anyLR + g*128 + k, bits);
      int wi = ptr-2; if (wi < 0) wi = 0; if (wi > T_+1) wi = T_+1;
      stk[wi] = (short)(REF_COMP + k);
      k++; ptr--;
    }                                  // SKIP: no change
    redL[b*STEPS_ + t] = (short)rl;
    redR[b*STEPS_ + t] = (short)rr;
  }
  for (int kk = k; kk < 128; kk++){
    uL[b*128+kk] = -1; uR[b*128+kk] = -1; cL[b*128+kk] = -1; cR[b*128+kk] = -1;
  }
  int ei = ptr-1; if (ei < 0) ei = 0; if (ei > T_+1) ei = T_+1;
  encRef[b] = stk[ei];
  nred[b] = k;
  atomicMax(gIter + g, k);
}

// ---------------- W prep: fp32 [1024][512] -> bf16 MFMA-B-fragment-linear ----
__global__ void k_wprep(const float* __restrict__ W, unsigned short* __restrict__ Wo){
  int t = blockIdx.x*256 + threadIdx.x;           // t < 524288
  int e  = t & 7;
  int l  = (t >> 3) & 63;
  int kt = (t >> 9) & 31;
  int nt = (t >> 14);
  int krow = kt*32 + (l >> 4)*8 + e;
  int ncol = nt*16 + (l & 15);
  Wo[t] = rne_bf16(W[krow*512 + ncol]);
}

// ---------------- U GEMM -> U3 (per-chain-thread contiguous 64B blocks) ------
// U3[((g*128+k)*256 + chainTid)*32 + j*8 + nt] = bf16(WL*left + WR*right + b)
__global__ __launch_bounds__(256) void k_ugemm(
    const float* __restrict__ bufs, const float* __restrict__ bias,
    const unsigned short* __restrict__ Wo,
    const short* __restrict__ uL, const short* __restrict__ uR,
    const float* __restrict__ zeroF, unsigned short* __restrict__ U3){
  int mt = blockIdx.x & 255, ntB = blockIdx.x >> 8;
  int w = threadIdx.x >> 6, lane = threadIdx.x & 63;
  int rbase = mt*64 + w*16;
  int arow = rbase + (lane & 15);
  int b = arow >> 7;
  int refL = (int)uL[arow], refR = (int)uR[arow];
  const float* pL = (refL >= 0) ? (bufs + ((size_t)b*T_ + refL)*D_) : zeroF;
  const float* pR = (refR >= 0) ? (bufs + ((size_t)b*T_ + refR)*D_) : zeroF;
  int eoff = (lane >> 4) * 8;
  float4v acc[8];
  #pragma unroll
  for (int nt = 0; nt < 8; ++nt) acc[nt] = (float4v){0.f,0.f,0.f,0.f};
  for (int kt = 0; kt < 32; ++kt){
    const float* src = (kt < 16) ? pL : pR;
    int off = (kt & 15)*32 + eoff;
    float4v f0 = *reinterpret_cast<const float4v*>(src + off);
    float4v f1 = *reinterpret_cast<const float4v*>(src + off + 4);
    short8 a;
    a[0]=(short)rne_bf16(f0[0]); a[1]=(short)rne_bf16(f0[1]);
    a[2]=(short)rne_bf16(f0[2]); a[3]=(short)rne_bf16(f0[3]);
    a[4]=(short)rne_bf16(f1[0]); a[5]=(short)rne_bf16(f1[1]);
    a[6]=(short)rne_bf16(f1[2]); a[7]=(short)rne_bf16(f1[3]);
    #pragma unroll
    for (int nt = 0; nt < 8; ++nt){
      const short8* bp = reinterpret_cast<const short8*>(Wo)
                         + (((size_t)(ntB*8 + nt)*32 + kt)*64 + lane);
      acc[nt] = __builtin_amdgcn_mfma_f32_16x16x32_bf16(a, *bp, acc[nt], 0, 0, 0);
    }
  }
  #pragma unroll
  for (int nt = 0; nt < 8; ++nt){
    int col = ntB*128 + nt*16 + (lane & 15);
    float bc = bias[col];
    int wq = col >> 7, ntl = (col >> 4) & 7, cl2 = col & 15;
    #pragma unroll
    for (int j2 = 0; j2 < 4; ++j2){
      int orow = rbase + (lane >> 4)*4 + j2;
      int bOut = orow >> 7, kOut = orow & 127;
      int jj = (bOut & 1) ? 64 + (bOut >> 1) : (bOut >> 1);
      int gO = jj >> 4, slot = jj & 15;
      int rqO = slot >> 2, jO = slot & 3;
      size_t off = (((size_t)(gO*128 + kOut)*256) + (size_t)(wq*64 + rqO*16 + cl2))*32
                   + jO*8 + ntl;
      U3[off] = rne_bf16(acc[nt][j2] + bc);
    }
  }
}

// ---------------- chain: 1 group = 1 WG = 1 CU; LDS exchange, no cross-CU ----
// 4 waves x 128 cols. W_L: 12 ktiles in VGPRs (384, compile-time-indexed),
// 4 ktiles in LDS (128 KB). c in 16 KB swizzled LDS buffer; raw s_barrier +
// lgkmcnt(0) only (no vmcnt drain). CompBf written with plain stores for k_out.
__global__ __launch_bounds__(256, 1) void k_chain11(
    const unsigned short* __restrict__ Wo, const unsigned short* __restrict__ U3,
    const short* __restrict__ cL, const short* __restrict__ cR,
    const int* __restrict__ nred, const int* __restrict__ gIter,
    const int* __restrict__ anyLR, const unsigned short* __restrict__ zeroPg,
    unsigned short* __restrict__ CompBf)
{
  __shared__ unsigned short SH[LDS_USHORTS];      // 128K W | 16K c | 1K zero
  const int tid = threadIdx.x, lane = tid & 63, w = tid >> 6;
  const int g = blockIdx.x;
  const int colLane = lane & 15, rq = lane >> 4;

  // init LDS: W ktiles 12..15 (frag-linear) + zero pad
  {
    const ushort8* src = reinterpret_cast<const ushort8*>(Wo);
    ushort8* dst = reinterpret_cast<ushort8*>(SH);
    for (int i = tid; i < 8192; i += 256){
      int ln = i & 63, ktl = (i >> 6) & 3, nt = i >> 8;
      dst[i] = src[((size_t)nt*32 + 12 + ktl)*64 + ln];
    }
    if (tid < 64) reinterpret_cast<ushort8*>((char*)SH + ZOFF)[tid] = (ushort8)0;
  }

  // W_L ktiles 0..11 -> VGPRs (all indices compile-time after unroll; rule #20)
  const short8* WoF = reinterpret_cast<const short8*>(Wo);
  short8 WV[8][12];
  #pragma unroll
  for (int ntl = 0; ntl < 8; ++ntl)
    #pragma unroll
    for (int kt = 0; kt < 12; ++kt)
      WV[ntl][kt] = WoF[((size_t)(w*8 + ntl)*32 + kt)*64 + lane];

  const int myb = rowB(g*16 + colLane);
  const int myNred = nred[myb];
  const int iters = gIter[g];
  int bS[4], nredS[4];
  #pragma unroll
  for (int j = 0; j < 4; ++j){
    bS[j] = rowB(g*16 + rq*4 + j);
    nredS[j] = nred[bS[j]];
  }
  const int aswz = (colLane & 7) << 4;

  asm volatile("s_waitcnt lgkmcnt(0)" ::: "memory");
  __builtin_amdgcn_s_barrier();                   // Wlds + zpad ready
  asm volatile("" ::: "memory");

  for (int k = 0; k < iters; ++k){
    const int afl = anyLR[g*128 + k];
    // U issue (consumed only at tanh; hidden under barrier + MFMA)
    const ushort8* up = reinterpret_cast<const ushort8*>(U3)
                        + ((size_t)(g*128 + k)*256 + tid)*4;
    ushort8 u0 = up[0], u1 = up[1], u2 = up[2], u3v = up[3];

    // barrier1: previous step's c writes visible (LDS only -> lgkm, no vmcnt)
    asm volatile("s_waitcnt lgkmcnt(0)" ::: "memory");
    __builtin_amdgcn_s_barrier();
    asm volatile("" ::: "memory");

    float4v acc[8];
    #pragma unroll
    for (int t = 0; t < 8; ++t) acc[t] = (float4v){0.f,0.f,0.f,0.f};

    if (afl & 1){                                 // dynamic left (the chain dep)
      int rl = (k < myNred) ? (int)cL[myb*128 + k] : -1;
      bool fast = __all(rl == k-1 || rl < 0);
      if (fast){
        // per-lane source: c_{k-1} row in LDS, or the zero pad
        const char* base = (const char*)SH + (rl < 0 ? ZOFF : COFF + colLane*1024);
        #pragma unroll
        for (int kt = 0; kt < 12; ++kt){
          short8 aL = *reinterpret_cast<const short8*>(base + ((kt*64 + rq*16) ^ aswz));
          #pragma unroll
          for (int t = 0; t < 8; ++t)
            acc[t] = __builtin_amdgcn_mfma_f32_16x16x32_bf16(aL, WV[t][kt], acc[t], 0, 0, 0);
        }
        #pragma unroll
        for (int ktl = 0; ktl < 4; ++ktl){
          short8 aL = *reinterpret_cast<const short8*>(base + ((((12+ktl)*64) + rq*16) ^ aswz));
          #pragma unroll
          for (int t = 0; t < 8; ++t){
            short8 bW = *reinterpret_cast<const short8*>(
              (const char*)SH + WOFF + ((((w*8 + t)*4 + ktl)*64 + lane) << 4));
            acc[t] = __builtin_amdgcn_mfma_f32_16x16x32_bf16(aL, bW, acc[t], 0, 0, 0);
          }
        }
      } else {
        // general fallback: left ref != k-1 -> per-lane row from global CompBf
        asm volatile("s_waitcnt vmcnt(0)" ::: "memory");
        const char* gp = (rl >= 0)
          ? (const char*)(CompBf + ((size_t)myb*128 + rl)*512)
          : (const char*)zeroPg;
        #pragma unroll
        for (int kt = 0; kt < 12; ++kt){
          short8 aL = *reinterpret_cast<const short8*>(gp + kt*64 + rq*16);
          #pragma unroll
          for (int t = 0; t < 8; ++t)
            acc[t] = __builtin_amdgcn_mfma_f32_16x16x32_bf16(aL, WV[t][kt], acc[t], 0, 0, 0);
        }
        #pragma unroll
        for (int ktl = 0; ktl < 4; ++ktl){
          short8 aL = *reinterpret_cast<const short8*>(gp + (12+ktl)*64 + rq*16);
          #pragma unroll
          for (int t = 0; t < 8; ++t){
            short8 bW = *reinterpret_cast<const short8*>(
              (const char*)SH + WOFF + ((((w*8 + t)*4 + ktl)*64 + lane) << 4));
            acc[t] = __builtin_amdgcn_mfma_f32_16x16x32_bf16(aL, bW, acc[t], 0, 0, 0);
          }
        }
      }
    }
    if (afl & 2){                                 // dynamic right (rare/general):
      int rr = (k < myNred) ? (int)cR[myb*128 + k] : -1;   // W_R frags from global Wo
      asm volatile("s_waitcnt vmcnt(0)" ::: "memory");
      const char* gp = (rr >= 0)
        ? (const char*)(CompBf + ((size_t)myb*128 + rr)*512)
        : (const char*)zeroPg;
      #pragma unroll 4
      for (int kt = 0; kt < 16; ++kt){
        short8 aR = *reinterpret_cast<const short8*>(gp + kt*64 + rq*16);
        #pragma unroll
        for (int t = 0; t < 8; ++t){
          short8 bW = WoF[((size_t)(w*8 + t)*32 + 16 + kt)*64 + lane];
          acc[t] = __builtin_amdgcn_mfma_f32_16x16x32_bf16(aR, bW, acc[t], 0, 0, 0);
        }
      }
    }

    // barrier2: all waves done READING c_{k-1}; safe to overwrite
    __builtin_amdgcn_s_barrier();
    asm volatile("" ::: "memory");

    // tanh(acc + U) -> cbuf (LDS, swizzled) + CompBf (plain global, for k_out)
    #pragma unroll
    for (int t = 0; t < 8; ++t){
      int colg = (w*8 + t)*16 + colLane;
      float v0 = fast_tanh(acc[t][0] + bf2f(u0[t]));
      float v1 = fast_tanh(acc[t][1] + bf2f(u1[t]));
      float v2 = fast_tanh(acc[t][2] + bf2f(u2[t]));
      float v3 = fast_tanh(acc[t][3] + bf2f(u3v[t]));
      unsigned short bv[4] = { rne_bf16(v0), rne_bf16(v1), rne_bf16(v2), rne_bf16(v3) };
      #pragma unroll
      for (int j = 0; j < 4; ++j){
        if (k < nredS[j])
          CompBf[((size_t)bS[j]*128 + k)*512 + colg] = bv[j];
        int slot = rq*4 + j;
        *reinterpret_cast<unsigned short*>(
          (char*)SH + COFF + slot*1024 + ((colg*2) ^ ((slot & 7) << 4))) = bv[j];
      }
    }
  }
}

// ---------------- output writer: pure copy/scatter, memory-bound ------------
__global__ __launch_bounds__(256) void k_out(
    const float* __restrict__ bufs, const unsigned short* __restrict__ CompBf,
    const short* __restrict__ redL, const short* __restrict__ redR,
    const int* __restrict__ encRef, float* __restrict__ out)
{
  int r = blockIdx.x*2 + (threadIdx.x >> 7);      // 65536 output rows of 512 f32
  int q = threadIdx.x & 127;                      // float4 index within row
  int ref, b;
  float* dst;
  if (r < B_){                                    // enc block
    b = r; ref = encRef[r];
    dst = out + (size_t)r*D_;
  } else {                                        // attended block
    int z = r - B_;
    b = z / 511; int s = z - b*511;
    dst = out + (size_t)B_*D_ + (size_t)z*D_;
    if (s == 510) ref = encRef[b];
    else { int t = s >> 1; ref = (s & 1) ? (int)redR[b*STEPS_ + t] : (int)redL[b*STEPS_ + t]; }
  }
  float4v v = {0.f, 0.f, 0.f, 0.f};
  if (ref >= 0 && ref < REF_COMP){
    v = reinterpret_cast<const float4v*>(bufs + ((size_t)b*T_ + ref)*D_)[q];
  } else if (ref >= REF_COMP && ref < REF_ZERO){
    ushort4v u = reinterpret_cast<const ushort4v*>(CompBf + ((size_t)b*128 + (ref - REF_COMP))*D_)[q];
    v[0] = bf2f(u[0]); v[1] = bf2f(u[1]); v[2] = bf2f(u[2]); v[3] = bf2f(u[3]);
  }
  reinterpret_cast<float4v*>(dst)[q] = v;
}

// ---------------- launch ----------------------------------------------------
extern "C" void kernel_launch(void* const* d_in, const int* in_sizes, int n_in,
                              void* d_out, int out_size, void* d_ws, size_t ws_size,
                              hipStream_t stream){
  const float* bufs = (const float*)d_in[0];
  const float* W    = (const float*)d_in[1];
  const float* bias = (const float*)d_in[2];
  const int*   tr   = (const int*)d_in[3];
  float* out = (float*)d_out;
  char* ws = (char*)d_ws;

  unsigned short* Wo     = (unsigned short*)(ws);               //  1,048,576
  unsigned short* CompBf = (unsigned short*)(ws + 1048576);     // 16,777,216
  unsigned short* U3     = (unsigned short*)(ws + 17825792);    // 16,777,216
  short* redL   = (short*)(ws + 34603008);                      //     65,536
  short* redR   = (short*)(ws + 34668544);                      //     65,536
  short* uL     = (short*)(ws + 34734080);                      //     32,768
  short* uR     = (short*)(ws + 34766848);                      //     32,768
  short* cL     = (short*)(ws + 34799616);                      //     32,768
  short* cR     = (short*)(ws + 34832384);                      //     32,768
  int* nred     = (int*)(ws + 34865152);                        //        512
  int* encRef   = (int*)(ws + 34865664);                        //        512
  int* gIter    = (int*)(ws + 34866176);                        //        256
  int* anyLR    = (int*)(ws + 34866432);                        //      4,096
  unsigned short* zeroPg = (unsigned short*)(ws + 34870528);    //      2,048

  k_zero<<<1, 256, 0, stream>>>(anyLR, gIter, zeroPg);
  k_prepass2<<<128, 64, 0, stream>>>(tr, redL, redR, uL, uR, cL, cR, nred, encRef, gIter, anyLR);
  k_wprep<<<2048, 256, 0, stream>>>(W, Wo);
  k_ugemm<<<1024, 256, 0, stream>>>(bufs, bias, Wo, uL, uR, (const float*)zeroPg, U3);
  k_chain11<<<8, 256, 0, stream>>>(Wo, U3, cL, cR, nred, gIter, anyLR, zeroPg, CompBf);
  k_out<<<32768, 256, 0, stream>>>(bufs, CompBf, redL, redR, encRef, out);
}